// Round 1
// baseline (160.989 us; speedup 1.0000x reference)
//
#include <hip/hip_runtime.h>
#include <math.h>

// EquiTritonModel: N=10000 nodes, E=160000 edges, D=32, H=16, NB=16.
// R14 -> R15: removed the slot-bucket indirection entirely.
//  - In-edge aggregation (z0, z1 = 64 floats/node, 2.56 MB) now uses
//    fire-and-forget global fp32 atomics (unsafeAtomicAdd -> native
//    global_atomic_add_f32, no return => no dependency stall). Replaces
//    atomicAdd-with-return slot counters + scattered 16B bucket stores
//    (50.5 MB written, 1.4x write-allocate amplification).
//  - Out-edge data (h1, unit vec) stored COALESCED by edge id; a second
//    cheap edge sweep reads them back against a 2.56 MB L2-resident Q/P
//    table produced by a tiny per-node transform kernel.
// Old node_kernel (~40us bucket round-trip) becomes node_qp (~4us) +
// edge2 (~7us).

namespace {
constexpr int   NATOMS   = 100;
constexpr float PI_F     = 3.14159265358979323846f;
constexpr float INV4PI_F = 0.28209479177387814f;   // 1/sqrt(4*pi)
constexpr float SQRT3_F  = 1.7320508075688772f;
constexpr float CUT_F    = 6.0f;
constexpr float BASIS_C  = 2.3094010767585034f;    // sqrt(2/6)*sqrt(16)
constexpr float N0_F     = 0.17677669529663687f;   // 1/sqrt(32)
constexpr float K0_F = INV4PI_F * N0_F * 0.0625f;  // m0 scale incl /DEG
constexpr float K1_F = SQRT3_F * INV4PI_F * N0_F * 0.0625f;
constexpr float P2SC = INV4PI_F * N0_F * (1.0f / 64.0f);
}

__device__ __forceinline__ float silu_fast(float x) {
  return x / (1.0f + __expf(-x));
}

__device__ __forceinline__ float block_reduce_sum(float v) {
  #pragma unroll
  for (int o = 32; o > 0; o >>= 1) v += __shfl_down(v, o, 64);
  __shared__ float ls[8];
  int lane = threadIdx.x & 63;
  int w    = threadIdx.x >> 6;
  if (lane == 0) ls[w] = v;
  __syncthreads();
  float s = 0.f;
  if (threadIdx.x == 0) {
    int nw = (blockDim.x + 63) >> 6;
    for (int i = 0; i < nw; ++i) s += ls[i];
  }
  return s;
}

// ---------------------------------------------------------------------------
// table_kernel: blocks [0,NATOMS) -> TI tables; block NATOMS -> G1T/G4T +
// out-zero; blocks > NATOMS zero zacc (N*64 floats) — no hipMemset needed.
// ---------------------------------------------------------------------------
__global__ void table_kernel(const float* __restrict__ atom_emb,
                             const float* __restrict__ fc0_w2,
                             const float* __restrict__ fc1_w2,
                             const float* __restrict__ w_readout,
                             float* __restrict__ TI,
                             float* __restrict__ G1T, float* __restrict__ G4T,
                             float* __restrict__ zacc,  // N*64 zeroed
                             float* __restrict__ out,
                             int N64) {
  int b = blockIdx.x;
  int tt = threadIdx.x;
  if (b < NATOMS) {
    int j = tt >> 4;
    int h = tt & 15;
    float s0 = 0.f, s1 = 0.f;
    #pragma unroll
    for (int d = 0; d < 32; ++d) {
      float x = atom_emb[b * 32 + d];
      s0 = fmaf(x, fc0_w2[j * 1024 + d * 16 + h], s0);
      s1 = fmaf(x, fc0_w2[j * 1024 + 512 + d * 16 + h], s1);
    }
    TI[b * 512 + j * 32 + 2 * h]     = s0;
    TI[b * 512 + j * 32 + 2 * h + 1] = s1;
  } else if (b == NATOMS) {
    int j = tt >> 4;
    int h = tt & 15;
    float g1 = 0.f, g4 = 0.f;
    #pragma unroll
    for (int k = 0; k < 16; ++k) {
      float r = w_readout[k];
      g1 = fmaf(fc1_w2[j * 1024 + h * 16 + k], r, g1);
      g4 = fmaf(fc1_w2[j * 1024 + 768 + h * 16 + k], r, g4);
    }
    G1T[h * 16 + j] = g1;
    G4T[h * 16 + j] = g4;
    if (tt == 0) *out = 0.f;
  } else {
    int idx = (b - NATOMS - 1) * 256 + tt;
    if (idx < N64) zacc[idx] = 0.f;
  }
}

// ---------------------------------------------------------------------------
// edge_kernel: 16 groups x 16 lanes; group handles edges b*32+g and
// b*32+16+g (2-edge ILP pipeline). Outputs:
//   - zacc[dst*64 + {t,16+t,32+t,48+t}] += {K0*u0, K1*u1*ux/uy/uz}
//     (fire-and-forget atomics, coalesced 64B segments per group)
//   - hbuf[e*16+t] = h1 (coalesced full-line stores by edge id)
//   - ubuf[e] = unit vector (coalesced by edge id)
// ---------------------------------------------------------------------------
__global__ void __launch_bounds__(256)
edge_kernel(const int* __restrict__ ei,
            const float* __restrict__ coords,
            const int* __restrict__ an,
            const float* __restrict__ TI,
            const float* __restrict__ fc0_w1,
            const float* __restrict__ fc1_w1,
            float* __restrict__ zacc,
            float* __restrict__ hbuf,
            float4* __restrict__ ubuf,
            int E) {
  int lane = threadIdx.x & 63;
  int g    = threadIdx.x >> 4;       // block group 0..15
  int t    = threadIdx.x & 15;
  int base = lane & 48;

  float w0c[16], w1c[16];
  #pragma unroll
  for (int k = 0; k < 16; ++k) {
    w0c[k] = fc0_w1[k * 16 + t];
    w1c[k] = fc1_w1[k * 16 + t];
  }

  const float angc = PI_F / CUT_F;
  int eA = blockIdx.x * 32 + g;
  int eB = eA + 16;
  bool vA = eA < E, vB = eB < E;
  int eAc = vA ? eA : 0, eBc = vB ? eB : 0;

  // ---- phase 1: all input loads ----
  int sA = ei[eAc], dA = ei[E + eAc];
  int sB = ei[eBc], dB = ei[E + eBc];
  float sxA = coords[3 * sA + 0], syA = coords[3 * sA + 1], szA = coords[3 * sA + 2];
  float dxA = coords[3 * dA + 0], dyA = coords[3 * dA + 1], dzA = coords[3 * dA + 2];
  float sxB = coords[3 * sB + 0], syB = coords[3 * sB + 1], szB = coords[3 * sB + 2];
  float dxB = coords[3 * dB + 0], dyB = coords[3 * dB + 1], dzB = coords[3 * dB + 2];
  int aA = an[sA], aB = an[sB];

  // ---- phase 2: geometry; unit-vec stores go out immediately ----
  float vxA = sxA - dxA, vyA = syA - dyA, vzA = szA - dzA;
  float vxB = sxB - dxB, vyB = syB - dyB, vzB = szB - dzB;
  float distA = sqrtf(vxA * vxA + vyA * vyA + vzA * vzA);
  float distB = sqrtf(vxB * vxB + vyB * vyB + vzB * vzB);
  float ivA = 1.0f / fmaxf(distA, 1e-9f);
  float ivB = 1.0f / fmaxf(distB, 1e-9f);
  float uxA = vxA * ivA, uyA = vyA * ivA, uzA = vzA * ivA;
  float uxB = vxB * ivB, uyB = vyB * ivB, uzB = vzB * ivB;
  float bcA = (distA < CUT_F) ? (BASIS_C * ivA) : 0.0f;
  float bcB = (distB < CUT_F) ? (BASIS_C * ivB) : 0.0f;

  if (t == 0) {
    if (vA) ubuf[eA] = make_float4(uxA, uyA, uzA, 0.f);
    if (vB) ubuf[eB] = make_float4(uxB, uyB, uzB, 0.f);
  }

  // ---- phase 3: interleaved sine recurrences (one chain per edge) ----
  float angA = angc * distA, angB = angc * distB;
  float scA = __sinf(angA), twA = 2.0f * __cosf(angA), spA = 0.f;
  float scB = __sinf(angB), twB = 2.0f * __cosf(angB), spB = 0.f;
  float a0A = 0.f, a1A = 0.f, a0B = 0.f, a1B = 0.f;
  #pragma unroll
  for (int k = 0; k < 16; ++k) {
    a0A = fmaf(scA, w0c[k], a0A);
    a1A = fmaf(scA, w1c[k], a1A);
    a0B = fmaf(scB, w0c[k], a0B);
    a1B = fmaf(scB, w1c[k], a1B);
    float snA = fmaf(twA, scA, -spA); spA = scA; scA = snA;
    float snB = fmaf(twB, scB, -spB); spB = scB; scB = snB;
  }
  float h0A = silu_fast(a0A * bcA * 0.25f);
  float h1A = silu_fast(a1A * bcA * 0.25f);
  float h0B = silu_fast(a0B * bcB * 0.25f);
  float h1B = silu_fast(a1B * bcB * 0.25f);

  // h1 stores (coalesced 64B/group) in flight before the contraction
  if (vA) hbuf[(size_t)eA * 16 + t] = h1A;
  if (vB) hbuf[(size_t)eB * 16 + t] = h1B;

  // ---- phase 4: interleaved TI loads + contraction ----
  const float2* tpA = (const float2*)(TI + aA * 512) + t;
  const float2* tpB = (const float2*)(TI + aB * 512) + t;
  float u0A = 0.f, u1A = 0.f, u0B = 0.f, u1B = 0.f;
  #pragma unroll
  for (int j = 0; j < 16; ++j) {
    float hjA = __shfl(h0A, base + j, 64);
    float hjB = __shfl(h0B, base + j, 64);
    float2 TA = tpA[j * 16];
    float2 TB = tpB[j * 16];
    u0A = fmaf(hjA, TA.x, u0A);
    u1A = fmaf(hjA, TA.y, u1A);
    u0B = fmaf(hjB, TB.x, u0B);
    u1B = fmaf(hjB, TB.y, u1B);
  }

  // ---- phase 5: fire-and-forget z-accumulation (no return => no stall) ----
  if (vA) {
    float* za = zacc + (size_t)dA * 64 + t;
    float m1 = K1_F * u1A;
    unsafeAtomicAdd(za,      K0_F * u0A);
    unsafeAtomicAdd(za + 16, m1 * uxA);
    unsafeAtomicAdd(za + 32, m1 * uyA);
    unsafeAtomicAdd(za + 48, m1 * uzA);
  }
  if (vB) {
    float* zb = zacc + (size_t)dB * 64 + t;
    float m1 = K1_F * u1B;
    unsafeAtomicAdd(zb,      K0_F * u0B);
    unsafeAtomicAdd(zb + 16, m1 * uxB);
    unsafeAtomicAdd(zb + 32, m1 * uyB);
    unsafeAtomicAdd(zb + 48, m1 * uzB);
  }
}

// ---------------------------------------------------------------------------
// node_qp_kernel: 16 nodes/block (16 lanes per node). Reads zacc, produces
// QP[n*64 + {t,16+t,32+t,48+t}] = {Q, Px, Py, Pz} and the readout term
// 0.25 * z0 . r (block-reduced into out).
// ---------------------------------------------------------------------------
__global__ void __launch_bounds__(256)
node_qp_kernel(const float* __restrict__ zacc,
               const float* __restrict__ G1T,
               const float* __restrict__ G4T,
               const float* __restrict__ w_readout,
               float* __restrict__ QP,
               float* __restrict__ out,
               int N) {
  __shared__ float ggs[512];          // [0:256)=G1T, [256:512)=G4T
  ggs[threadIdx.x]       = G1T[threadIdx.x];
  ggs[256 + threadIdx.x] = G4T[threadIdx.x];
  __syncthreads();

  int lane = threadIdx.x & 63;
  int t    = lane & 15;
  int base = lane & 48;
  int node = blockIdx.x * 16 + (threadIdx.x >> 4);
  bool valid = node < N;
  size_t nb = (size_t)(valid ? node : 0) * 64;

  float z0 = zacc[nb + t];
  float zx = zacc[nb + 16 + t];
  float zy = zacc[nb + 32 + t];
  float zz = zacc[nb + 48 + t];

  float Q = 0.f, Px = 0.f, Py = 0.f, Pz = 0.f;
  #pragma unroll
  for (int h = 0; h < 16; ++h) {
    float z0h = __shfl(z0, base + h, 64);
    float zxh = __shfl(zx, base + h, 64);
    float zyh = __shfl(zy, base + h, 64);
    float zzh = __shfl(zz, base + h, 64);
    float g1 = ggs[h * 16 + t];
    float g4 = ggs[256 + h * 16 + t];
    Q  = fmaf(g1, z0h, Q);
    Px = fmaf(g4, zxh, Px);
    Py = fmaf(g4, zyh, Py);
    Pz = fmaf(g4, zzh, Pz);
  }
  if (valid) {
    QP[nb + t]      = Q;
    QP[nb + 16 + t] = Px;
    QP[nb + 32 + t] = Py;
    QP[nb + 48 + t] = Pz;
  }

  float c = valid ? 0.25f * z0 * w_readout[t] : 0.f;
  float tot = block_reduce_sum(c);
  if (threadIdx.x == 0) atomicAdd(out, tot);
}

// ---------------------------------------------------------------------------
// edge2_kernel: grid-stride sweep over edges. Per 16-lane group / edge:
// coalesced h1 + broadcast unit vec + 4 gathered 64B segments from the
// L2-resident QP table. One block reduce + atomic per block.
// ---------------------------------------------------------------------------
__global__ void __launch_bounds__(256)
edge2_kernel(const int* __restrict__ ei,
             const float4* __restrict__ ubuf,
             const float* __restrict__ hbuf,
             const float* __restrict__ QP,
             float* __restrict__ out,
             int E) {
  int t  = threadIdx.x & 15;
  int gg = blockIdx.x * 16 + (threadIdx.x >> 4);
  int ngroups = gridDim.x * 16;

  float c = 0.f;
  for (int e = gg; e < E; e += ngroups) {
    int s = ei[e];
    float4 u = ubuf[e];
    float h1 = hbuf[(size_t)e * 16 + t];
    size_t sb = (size_t)s * 64;
    float Qt  = QP[sb + t];
    float Pxt = QP[sb + 16 + t];
    float Pyt = QP[sb + 32 + t];
    float Pzt = QP[sb + 48 + t];
    c = fmaf(h1, fmaf(Pxt, u.x, fmaf(Pyt, u.y, fmaf(Pzt, u.z, Qt))), c);
  }
  c *= P2SC;
  float tot = block_reduce_sum(c);
  if (threadIdx.x == 0) atomicAdd(out, tot);
}

extern "C" void kernel_launch(void* const* d_in, const int* in_sizes, int n_in,
                              void* d_out, int out_size, void* d_ws, size_t ws_size,
                              hipStream_t stream) {
  const int*   an        = (const int*)d_in[0];
  const float* coords    = (const float*)d_in[1];
  const int*   ei        = (const int*)d_in[2];
  const float* atom_emb  = (const float*)d_in[3];
  const float* fc0_w1    = (const float*)d_in[4];
  const float* fc0_w2    = (const float*)d_in[5];
  const float* fc1_w1    = (const float*)d_in[6];
  const float* fc1_w2    = (const float*)d_in[7];
  const float* w_readout = (const float*)d_in[8];

  int N = in_sizes[0];
  int E = in_sizes[2] / 2;
  int N64 = N * 64;

  // ws layout (16B-aligned arrays first). Total ~18 MB of ~256 MB ws.
  float4* ubuf = (float4*)d_ws;                 // E           (2.6 MB)
  float*  hbuf = (float*)(ubuf + E);            // E*16        (10.2 MB)
  float*  zacc = hbuf + (size_t)E * 16;         // N*64        (2.6 MB)
  float*  QP   = zacc + N64;                    // N*64        (2.6 MB)
  float*  TI   = QP + N64;                      // 100*512
  float*  G1T  = TI + NATOMS * 512;             // 256
  float*  G4T  = G1T + 256;                     // 256
  float*  out  = (float*)d_out;

  int blk = 256;
  int zgrid = (N64 + blk - 1) / blk;
  table_kernel<<<NATOMS + 1 + zgrid, blk, 0, stream>>>(
      atom_emb, fc0_w2, fc1_w2, w_readout, TI, G1T, G4T, zacc, out, N64);

  edge_kernel<<<(E + 31) / 32, blk, 0, stream>>>(
      ei, coords, an, TI, fc0_w1, fc1_w1, zacc, hbuf, ubuf, E);

  node_qp_kernel<<<(N + 15) / 16, blk, 0, stream>>>(
      zacc, G1T, G4T, w_readout, QP, out, N);

  edge2_kernel<<<2048, blk, 0, stream>>>(ei, ubuf, hbuf, QP, out, E);
}